// Round 2
// baseline (5823.117 us; speedup 1.0000x reference)
//
#include <hip/hip_runtime.h>
#include <stdint.h>

#define L_SEQ 2048
#define DM 1024
#define NH 16
#define DFF 4096
#define NB 4
#define ROWS (NB * L_SEQ)   // 8192

typedef __attribute__((ext_vector_type(8))) __bf16 bf16x8;
typedef __attribute__((ext_vector_type(4))) float f32x4;

__device__ __forceinline__ float bf2f(unsigned short u) {
  union { unsigned int i; float f; } x; x.i = ((unsigned int)u) << 16; return x.f;
}
__device__ __forceinline__ unsigned short f2bf(float f) {
  union { float f; unsigned int i; } x; x.f = f;
  unsigned int r = x.i + 0x7FFFu + ((x.i >> 16) & 1u);
  return (unsigned short)(r >> 16);
}

#if defined(__has_builtin)
#if __has_builtin(__builtin_amdgcn_global_load_lds)
#define HAVE_GLL 1
#endif
#endif
#ifndef HAVE_GLL
#define HAVE_GLL 0
#endif

typedef __attribute__((address_space(3))) void lds_void;
typedef const __attribute__((address_space(1))) void gbl_void;

// lane i's 16 bytes land at ldsbase + i*16 (wave-uniform base, per guide m104/m108)
__device__ __forceinline__ void stage16(const void* g, void* ldsbase, int lane) {
#if HAVE_GLL
  (void)lane;
  __builtin_amdgcn_global_load_lds((gbl_void*)g, (lds_void*)ldsbase, 16, 0, 0);
#else
  ((uint4*)ldsbase)[lane] = *(const uint4*)g;
#endif
}

// ---------------------------------------------------------------------------
// C[M=8192, N] = A[8192, K] * B[N, K]^T (+bias) (+act), bf16 in, f32 acc.
// m97-style: 128x128 tile, BK=32, 4 waves, 16x16x32 MFMA, global_load_lds w=16.
// act: 0=none, 1=relu, 2=sigmoid. Writes bf16 C16 and/or f32 C32 (ldc stride).
// ---------------------------------------------------------------------------
__global__ __launch_bounds__(256)
void gemm_bt(const unsigned short* __restrict__ A,
             const unsigned short* __restrict__ B,
             const float* __restrict__ bias,
             unsigned short* __restrict__ C16,
             float* __restrict__ C32,
             int K, int ldc, int n_limit, int act)
{
  __shared__ __attribute__((aligned(16))) unsigned short As[128 * 32];
  __shared__ __attribute__((aligned(16))) unsigned short Bs[128 * 32];
  const int tid  = threadIdx.x;
  const int wave = tid >> 6, lane = tid & 63;
  const int wm = (wave & 1) << 6, wn = (wave >> 1) << 6;
  const int l16 = lane & 15, quad = lane >> 4;

  const unsigned short* Ab = A + (size_t)blockIdx.x * 128 * K;
  const unsigned short* Bb = B + (size_t)blockIdx.y * 128 * K;

  const int srow = (wave << 4) + (lane >> 2);   // 0..63
  const int scol = (lane & 3) << 3;

  f32x4 acc[4][4] = {};

  for (int k0 = 0; k0 < K; k0 += 32) {
    const size_t aoff = (size_t)srow * K + k0 + scol;
    stage16(Ab + aoff,                  &As[(wave * 16) * 32],       lane);
    stage16(Ab + aoff + (size_t)64 * K, &As[(wave * 16 + 64) * 32], lane);
    stage16(Bb + aoff,                  &Bs[(wave * 16) * 32],       lane);
    stage16(Bb + aoff + (size_t)64 * K, &Bs[(wave * 16 + 64) * 32], lane);
    __syncthreads();

    bf16x8 af[4], bfr[4];
#pragma unroll
    for (int mi = 0; mi < 4; mi++)
      af[mi] = *(const bf16x8*)&As[(wm + mi * 16 + l16) * 32 + quad * 8];
#pragma unroll
    for (int ni = 0; ni < 4; ni++)
      bfr[ni] = *(const bf16x8*)&Bs[(wn + ni * 16 + l16) * 32 + quad * 8];
#pragma unroll
    for (int mi = 0; mi < 4; mi++)
#pragma unroll
      for (int ni = 0; ni < 4; ni++)
        acc[mi][ni] = __builtin_amdgcn_mfma_f32_16x16x32_bf16(af[mi], bfr[ni], acc[mi][ni], 0, 0, 0);
    __syncthreads();
  }

  const int row0 = (int)blockIdx.x * 128 + wm + quad * 4;
  const int col0 = (int)blockIdx.y * 128 + wn + l16;
#pragma unroll
  for (int ni = 0; ni < 4; ni++) {
    const int col = col0 + ni * 16;
    if (col >= n_limit) continue;
    const float bv = bias ? bias[col] : 0.0f;
#pragma unroll
    for (int mi = 0; mi < 4; mi++) {
#pragma unroll
      for (int r = 0; r < 4; r++) {
        const int row = row0 + mi * 16 + r;
        float v = acc[mi][ni][r] + bv;
        if (act == 1) v = fmaxf(v, 0.0f);
        else if (act == 2) v = 1.0f / (1.0f + __expf(-v));
        if (C32) C32[(size_t)row * ldc + col] = v;
        if (C16) C16[(size_t)row * ldc + col] = f2bf(v);
      }
    }
  }
}

// ---------------------------------------------------------------------------
// Fused flow attention, one block per (b,h). Q,K pre-sigmoided (GEMM epilogue).
// Stages 1-4: vector reductions; stages 5 (kv=K^T·(V*ncr)) and 6 (Q·kv): MFMA.
// O written in-place over V's (b,h) slice (V fully consumed in stage 5).
// NOTE: V and O intentionally alias — no __restrict__ on them.
// ---------------------------------------------------------------------------
__global__ __launch_bounds__(256)
void flow_attn(const unsigned short* __restrict__ Q,
               const unsigned short* __restrict__ K,
               const unsigned short* V,
               unsigned short* O)
{
  const int bh = blockIdx.x;                  // 0..63
  const size_t base = ((size_t)(bh >> 4) * L_SEQ) * DM + (size_t)(bh & 15) * 64;
  const int t = threadIdx.x;
  const int lane = t & 63, wave = t >> 6;
  const int l16 = lane & 15, quad = lane >> 4;
  const float eps = 1e-6f;

  __shared__ float s_nr[L_SEQ];     // nr, later nr*nrr
  __shared__ float s_sc[L_SEQ];     // nc, later softmax p
  __shared__ float s_ksum[64], s_qsum[64], s_t1[64], s_t2[64];
  __shared__ float s_red[256];
  __shared__ __attribute__((aligned(16))) unsigned short s_kT[64 * 72];  // [d][l] bf16
  __shared__ __attribute__((aligned(16))) unsigned short s_vT[64 * 72];  // [e][l] bf16 (ncr-weighted)
  __shared__ __attribute__((aligned(16))) unsigned short s_kvT[64 * 72]; // [e][d] bf16

  // ---- Stage 1: ksum[d], qsum[d]
  {
    float ks = 0.f, qs = 0.f;
    for (int l = wave; l < L_SEQ; l += 4) {
      const size_t idx = base + (size_t)l * DM + lane;
      ks += bf2f(K[idx]);
      qs += bf2f(Q[idx]);
    }
    s_red[t] = ks; __syncthreads();
    if (t < 64) s_ksum[t] = s_red[t] + s_red[t + 64] + s_red[t + 128] + s_red[t + 192];
    __syncthreads();
    s_red[t] = qs; __syncthreads();
    if (t < 64) s_qsum[t] = s_red[t] + s_red[t + 64] + s_red[t + 128] + s_red[t + 192];
    __syncthreads();
  }

  // ---- Stage 2: nr[l] = 1/dot(q+eps, ksum+eps); nc[l] = 1/dot(k+eps, qsum+eps)
  {
    const float kse = s_ksum[lane] + eps;
    const float qse = s_qsum[lane] + eps;
    for (int l = wave; l < L_SEQ; l += 4) {
      const size_t idx = base + (size_t)l * DM + lane;
      float a = (bf2f(Q[idx]) + eps) * kse;
      float c = (bf2f(K[idx]) + eps) * qse;
#pragma unroll
      for (int off = 32; off; off >>= 1) { a += __shfl_xor(a, off); c += __shfl_xor(c, off); }
      if (lane == 0) { s_nr[l] = 1.f / a; s_sc[l] = 1.f / c; }
    }
    __syncthreads();
  }

  // ---- Stage 3: t1[d] = sum_l k*nc ; t2[d] = sum_l q*nr
  {
    float t1 = 0.f, t2 = 0.f;
    for (int l = wave; l < L_SEQ; l += 4) {
      const size_t idx = base + (size_t)l * DM + lane;
      t1 += bf2f(K[idx]) * s_sc[l];
      t2 += bf2f(Q[idx]) * s_nr[l];
    }
    s_red[t] = t1; __syncthreads();
    if (t < 64) s_t1[t] = s_red[t] + s_red[t + 64] + s_red[t + 128] + s_red[t + 192];
    __syncthreads();
    s_red[t] = t2; __syncthreads();
    if (t < 64) s_t2[t] = s_red[t] + s_red[t + 64] + s_red[t + 128] + s_red[t + 192];
    __syncthreads();
  }

  // ---- Stage 4: nrr[l] folded into s_nr; raw ncr scores + softmax
  {
    const float t1e = s_t1[lane] + eps;
    const float t2e = s_t2[lane] + eps;
    for (int l = wave; l < L_SEQ; l += 4) {
      const size_t idx = base + (size_t)l * DM + lane;
      float a = (bf2f(Q[idx]) + eps) * t1e;
      float c = (bf2f(K[idx]) + eps) * t2e;
#pragma unroll
      for (int off = 32; off; off >>= 1) { a += __shfl_xor(a, off); c += __shfl_xor(c, off); }
      if (lane == 0) {
        s_nr[l] = s_nr[l] * (1.f / (1.f + __expf(-a)));   // nr * nrr
        s_sc[l] = c;                                      // raw score
      }
    }
    __syncthreads();
    float m = -3.4e38f;
    for (int l = t; l < L_SEQ; l += 256) m = fmaxf(m, s_sc[l]);
    s_red[t] = m; __syncthreads();
    for (int s = 128; s > 0; s >>= 1) { if (t < s) s_red[t] = fmaxf(s_red[t], s_red[t + s]); __syncthreads(); }
    const float mx = s_red[0];
    __syncthreads();
    float ps = 0.f;
    for (int l = t; l < L_SEQ; l += 256) { float p = __expf(s_sc[l] - mx); s_sc[l] = p; ps += p; }
    s_red[t] = ps; __syncthreads();
    for (int s = 128; s > 0; s >>= 1) { if (t < s) s_red[t] += s_red[t + s]; __syncthreads(); }
  }
  const float ncr_scale = (float)L_SEQ / s_red[0];   // ncr[l] = p[l]*ncr_scale

  // ---- Stage 5 (MFMA): kv[d][e] = sum_l k[l,d] * (v[l,e]*ncr[l])
  {
    f32x4 acc5[4] = {};
    for (int l0 = 0; l0 < L_SEQ; l0 += 64) {
#pragma unroll
      for (int it = 0; it < 4; it++) {
        const int task = it * 256 + t;     // 0..1023
        const int l = task >> 4;           // 0..63
        const int g = task & 15;           // d-group of 4
        const size_t gidx = base + (size_t)(l0 + l) * DM + g * 4;
        const ushort4 k4 = *(const ushort4*)(K + gidx);
        const ushort4 v4 = *(const ushort4*)(V + gidx);
        const float wgt = s_sc[l0 + l] * ncr_scale;
        s_kT[(g * 4 + 0) * 72 + l] = k4.x;
        s_kT[(g * 4 + 1) * 72 + l] = k4.y;
        s_kT[(g * 4 + 2) * 72 + l] = k4.z;
        s_kT[(g * 4 + 3) * 72 + l] = k4.w;
        s_vT[(g * 4 + 0) * 72 + l] = f2bf(bf2f(v4.x) * wgt);
        s_vT[(g * 4 + 1) * 72 + l] = f2bf(bf2f(v4.y) * wgt);
        s_vT[(g * 4 + 2) * 72 + l] = f2bf(bf2f(v4.z) * wgt);
        s_vT[(g * 4 + 3) * 72 + l] = f2bf(bf2f(v4.w) * wgt);
      }
      __syncthreads();
#pragma unroll
      for (int ks = 0; ks < 2; ks++) {
        const bf16x8 af = *(const bf16x8*)&s_kT[(wave * 16 + l16) * 72 + ks * 32 + quad * 8];
#pragma unroll
        for (int et = 0; et < 4; et++) {
          const bf16x8 bf = *(const bf16x8*)&s_vT[(et * 16 + l16) * 72 + ks * 32 + quad * 8];
          acc5[et] = __builtin_amdgcn_mfma_f32_16x16x32_bf16(af, bf, acc5[et], 0, 0, 0);
        }
      }
      __syncthreads();
    }
    // C layout: row(d-in-16)=quad*4+r, col(e-in-16)=l16 -> store kv^T[e][d] bf16
#pragma unroll
    for (int et = 0; et < 4; et++)
#pragma unroll
      for (int r = 0; r < 4; r++)
        s_kvT[(et * 16 + l16) * 72 + (wave * 16 + quad * 4 + r)] = f2bf(acc5[et][r]);
  }
  __syncthreads();

  // ---- Stage 6 (MFMA): O[l][e] = (sum_d q[l,d]*kv[d,e]) * nr[l]*nrr[l]
  {
    bf16x8 bfr6[4][2];
#pragma unroll
    for (int et = 0; et < 4; et++)
#pragma unroll
      for (int ks = 0; ks < 2; ks++)
        bfr6[et][ks] = *(const bf16x8*)&s_kvT[(et * 16 + l16) * 72 + ks * 32 + quad * 8];

    for (int lt = wave; lt < L_SEQ / 16; lt += 4) {
      const int l0 = lt * 16;
      f32x4 oc[4] = {};
#pragma unroll
      for (int ks = 0; ks < 2; ks++) {
        const bf16x8 aq = *(const bf16x8*)(Q + base + (size_t)(l0 + l16) * DM + ks * 32 + quad * 8);
#pragma unroll
        for (int et = 0; et < 4; et++)
          oc[et] = __builtin_amdgcn_mfma_f32_16x16x32_bf16(aq, bfr6[et][ks], oc[et], 0, 0, 0);
      }
#pragma unroll
      for (int et = 0; et < 4; et++) {
#pragma unroll
        for (int r = 0; r < 4; r++) {
          const int l = l0 + quad * 4 + r;
          const float sc = s_nr[l];
          O[base + (size_t)l * DM + et * 16 + l16] = f2bf(oc[et][r] * sc);
        }
      }
    }
  }
}

// ---------------------------------------------------------------------------
// LayerNorm over last dim (1024): out = LN(res (+ add)) * w + b. 1 wave/row.
// res/out32 may alias (in-place per-row) — no __restrict__ on them.
// ---------------------------------------------------------------------------
__global__ __launch_bounds__(256)
void ln_fused(const float* res, const float* __restrict__ add,
              const float* __restrict__ w, const float* __restrict__ bb,
              float* out32, unsigned short* out16)
{
  const int row = blockIdx.x * 4 + (threadIdx.x >> 6);
  const int lane = threadIdx.x & 63;
  const size_t roff = (size_t)row * DM;
  const float4* rp = (const float4*)(res + roff);
  const float4* ap = add ? (const float4*)(add + roff) : nullptr;

  float x[16], s = 0.f, s2 = 0.f;
#pragma unroll
  for (int q4 = 0; q4 < 4; q4++) {
    float4 v = rp[lane * 4 + q4];
    if (ap) { float4 a = ap[lane * 4 + q4]; v.x += a.x; v.y += a.y; v.z += a.z; v.w += a.w; }
    x[q4 * 4 + 0] = v.x; x[q4 * 4 + 1] = v.y; x[q4 * 4 + 2] = v.z; x[q4 * 4 + 3] = v.w;
    s += v.x + v.y + v.z + v.w;
    s2 += v.x * v.x + v.y * v.y + v.z * v.z + v.w * v.w;
  }
#pragma unroll
  for (int off = 32; off; off >>= 1) { s += __shfl_xor(s, off); s2 += __shfl_xor(s2, off); }
  const float mean = s * (1.f / DM);
  const float var = s2 * (1.f / DM) - mean * mean;
  const float rstd = rsqrtf(var + 1e-5f);
#pragma unroll
  for (int j = 0; j < 16; j++) {
    const int c = lane * 16 + j;
    x[j] = (x[j] - mean) * rstd * w[c] + bb[c];
  }
  if (out32) {
    float4* op = (float4*)(out32 + roff);
#pragma unroll
    for (int q4 = 0; q4 < 4; q4++) {
      float4 v; v.x = x[q4*4+0]; v.y = x[q4*4+1]; v.z = x[q4*4+2]; v.w = x[q4*4+3];
      op[lane * 4 + q4] = v;
    }
  }
  if (out16) {
#pragma unroll
    for (int q4 = 0; q4 < 4; q4++) {
      ushort4 u;
      u.x = f2bf(x[q4*4+0]); u.y = f2bf(x[q4*4+1]); u.z = f2bf(x[q4*4+2]); u.w = f2bf(x[q4*4+3]);
      *(ushort4*)(out16 + roff + lane * 16 + q4 * 4) = u;
    }
  }
}

// ---------------------------------------------------------------------------
// Channel attention helpers
// ---------------------------------------------------------------------------
__global__ void ca_zero(float* __restrict__ ybar) {
  const int i = blockIdx.x * 256 + threadIdx.x;
  if (i < NB * DM) ybar[i] = 0.f;
}
__global__ void ca_mean(const unsigned short* __restrict__ H16, float* __restrict__ ybar) {
  const int b = blockIdx.x, cc = blockIdx.y, lc = blockIdx.z;
  const int c = cc * 256 + threadIdx.x;
  float s = 0.f;
  for (int l = lc * 256; l < lc * 256 + 256; l++)
    s += bf2f(H16[((size_t)(b * L_SEQ + l)) * DM + c]);
  atomicAdd(&ybar[b * DM + c], s);
}
__global__ void ca_gate(const float* __restrict__ ybar, const float* __restrict__ cw,
                        float* __restrict__ gate) {
  const int i = blockIdx.x * 256 + threadIdx.x;
  if (i >= NB * DM) return;
  const int b = i >> 10, c = i & 1023;
  float acc = 0.f;
#pragma unroll
  for (int j = 0; j < 5; j++) {
    const int cc = c + j - 2;
    const float yv = (cc >= 0 && cc < DM) ? ybar[b * DM + cc] * (1.f / L_SEQ) : 0.f;
    acc += cw[j] * yv;
  }
  gate[i] = 1.f / (1.f + __expf(-acc));
}
__global__ void ca_apply(float* __restrict__ H32, unsigned short* __restrict__ H16,
                         const float* __restrict__ gate) {
  const size_t i = ((size_t)blockIdx.x * 256 + threadIdx.x) * 4;
  const int row = (int)(i >> 10);
  const int b = row >> 11;
  const int c = (int)(i & 1023);
  float4 v = *(float4*)(H32 + i);
  v.x *= gate[b * DM + c + 0];
  v.y *= gate[b * DM + c + 1];
  v.z *= gate[b * DM + c + 2];
  v.w *= gate[b * DM + c + 3];
  *(float4*)(H32 + i) = v;
  unsigned short* hp = H16 + i;
  hp[0] = f2bf(v.x); hp[1] = f2bf(v.y); hp[2] = f2bf(v.z); hp[3] = f2bf(v.w);
}

// ---------------------------------------------------------------------------
// f32 -> bf16 conversions: embed im2col, tok-weight repack, proj pad,
// per-layer weight conversion (Wq,Wk,Wv,Wo -> Wl; c1,c2 -> WlFF).
// ---------------------------------------------------------------------------
__global__ void embed_gather(const float* __restrict__ x, unsigned short* __restrict__ Ae) {
  const int i = blockIdx.x * 256 + threadIdx.x;
  if (i >= ROWS * 192) return;
  const int row = i / 192, kk = i % 192;
  const int t3 = kk >> 6, c = kk & 63;
  const int b = row >> 11, l = row & 2047;
  const int ls = (l + t3 - 1 + L_SEQ) & 2047;
  Ae[i] = f2bf(x[((size_t)(b * L_SEQ + ls)) * 64 + c]);
}
__global__ void embed_repack(const float* __restrict__ w, unsigned short* __restrict__ We) {
  const int i = blockIdx.x * 256 + threadIdx.x;
  if (i >= DM * 192) return;
  const int f = i / 192, kk = i % 192;
  const int t3 = kk >> 6, c = kk & 63;
  We[i] = f2bf(w[(f * 64 + c) * 3 + t3]);
}
__global__ void pad_proj(const float* __restrict__ pw, unsigned short* __restrict__ Wp) {
  const int i = blockIdx.x * 256 + threadIdx.x;
  if (i >= 128 * DM) return;
  Wp[i] = ((i >> 10) < 64) ? f2bf(pw[i]) : (unsigned short)0;
}
// 12M scalar elements as 3M float4s: [0,4M): Wq/Wk/Wv/Wo (1M each); [4M,12M): c1,c2 (4M each)
__global__ void cvt_layer_weights(const float* __restrict__ Wq, const float* __restrict__ Wk,
                                  const float* __restrict__ Wv, const float* __restrict__ Wo,
                                  const float* __restrict__ c1, const float* __restrict__ c2,
                                  unsigned short* __restrict__ Wl, unsigned short* __restrict__ WlFF) {
  const int g = blockIdx.x * 256 + threadIdx.x;   // 0..3M-1 float4 units
  const int i = g << 2;                           // scalar index
  const float* src; unsigned short* dst;
  if (i < (1 << 22)) {
    const int w = i >> 20, off = i & ((1 << 20) - 1);
    const float* srcs[4] = {Wq, Wk, Wv, Wo};
    src = srcs[w] + off; dst = Wl + (w << 20) + off;
  } else {
    const int j = i - (1 << 22);
    const int w = j >> 22, off = j & ((1 << 22) - 1);
    src = (w ? c2 : c1) + off; dst = WlFF + (w << 22) + off;
  }
  const float4 v = *(const float4*)src;
  ushort4 u; u.x = f2bf(v.x); u.y = f2bf(v.y); u.z = f2bf(v.z); u.w = f2bf(v.w);
  *(ushort4*)dst = u;
}

// ---------------------------------------------------------------------------
extern "C" void kernel_launch(void* const* d_in, const int* in_sizes, int n_in,
                              void* d_out, int out_size, void* d_ws, size_t ws_size,
                              hipStream_t stream) {
  const float* x     = (const float*)d_in[0];
  const float* tokw  = (const float*)d_in[1];
  const float* Wq    = (const float*)d_in[2];
  const float* bq    = (const float*)d_in[3];
  const float* Wk    = (const float*)d_in[4];
  const float* bk    = (const float*)d_in[5];
  const float* Wv    = (const float*)d_in[6];
  const float* bv    = (const float*)d_in[7];
  const float* Wo    = (const float*)d_in[8];
  const float* bo    = (const float*)d_in[9];
  const float* c1w   = (const float*)d_in[10];
  const float* c1b   = (const float*)d_in[11];
  const float* c2w   = (const float*)d_in[12];
  const float* c2b   = (const float*)d_in[13];
  const float* ln1w  = (const float*)d_in[14];
  const float* ln1b  = (const float*)d_in[15];
  const float* ln2w  = (const float*)d_in[16];
  const float* ln2b  = (const float*)d_in[17];
  const float* caw   = (const float*)d_in[18];
  const float* lnfw  = (const float*)d_in[19];
  const float* lnfb  = (const float*)d_in[20];
  const float* projw = (const float*)d_in[21];
  const float* projb = (const float*)d_in[22];

  char* ws = (char*)d_ws;
  // Activations: R32 (f32 residual), R16 (bf16 mirror), A32 (f32 GEMM out),
  // U (64MB union: Q|K|V during attention, F16 during FFN, Ae/Xf otherwise)
  float*          R32 = (float*)(ws);                               // 32 MB
  unsigned short* R16 = (unsigned short*)(ws + ((size_t)32 << 20)); // 16 MB
  float*          A32 = (float*)(ws + ((size_t)48 << 20));          // 32 MB
  unsigned short* U   = (unsigned short*)(ws + ((size_t)80 << 20)); // 64 MB
  unsigned short* Q16 = U;                                          // 16 MB
  unsigned short* K16 = U + ((size_t)8 << 20);                      // 16 MB
  unsigned short* V16 = U + ((size_t)16 << 20);                     // 16 MB
  unsigned short* F16 = U;                                          // 64 MB (FFN)
  unsigned short* Wl   = (unsigned short*)(ws + ((size_t)144 << 20)); // 8 MB  (Wq,Wk,Wv,Wo bf16)
  unsigned short* WlFF = (unsigned short*)(ws + ((size_t)152 << 20)); // 16 MB (c1,c2 bf16)
  char* misc = ws + ((size_t)168 << 20);
  float*          ybar = (float*)misc;                              // 16 KB
  float*          gate = (float*)(misc + (16 << 10));               // 16 KB
  unsigned short* We   = (unsigned short*)(misc + (64 << 10));      // 384 KB
  unsigned short* Wp   = (unsigned short*)(misc + (512 << 10));     // 256 KB

  const int BIG = 1 << 30;
  auto gemm = [&](const unsigned short* A, const unsigned short* B, const float* bias,
                  unsigned short* C16, float* C32, int N, int K, int ldc, int nlim, int act) {
    dim3 grid(ROWS / 128, N / 128);
    gemm_bt<<<grid, dim3(256), 0, stream>>>(A, B, bias, C16, C32, K, ldc, nlim, act);
  };

  // ---- token embedding (circular conv k=3 as im2col GEMM) -> R (f32 + bf16)
  embed_gather<<<(ROWS * 192 + 255) / 256, 256, 0, stream>>>(x, U);
  embed_repack<<<(DM * 192 + 255) / 256, 256, 0, stream>>>(tokw, We);
  gemm(U, We, nullptr, R16, R32, DM, 192, DM, BIG, 0);

  // ---- 4 encoder layers (+CA), then layer 3 re-applied (faithful to reference)
  for (int it = 0; it < 5; it++) {
    const int i = (it < 4) ? it : 3;
    if (it != 4) {  // it==4 reuses layer-3 weights already converted at it==3
      cvt_layer_weights<<<(3 << 20) / 256, 256, 0, stream>>>(
          Wq + ((size_t)i << 20), Wk + ((size_t)i << 20),
          Wv + ((size_t)i << 20), Wo + ((size_t)i << 20),
          c1w + ((size_t)i << 22), c2w + ((size_t)i << 22), Wl, WlFF);
    }
    const unsigned short* Wq16 = Wl;
    const unsigned short* Wk16 = Wl + (1 << 20);
    const unsigned short* Wv16 = Wl + (2 << 20);
    const unsigned short* Wo16 = Wl + (3 << 20);
    const unsigned short* C116 = WlFF;
    const unsigned short* C216 = WlFF + (1 << 22);

    gemm(R16, Wq16, bq + i * DM, Q16, nullptr, DM, DM, DM, BIG, 2); // sigmoid(q)
    gemm(R16, Wk16, bk + i * DM, K16, nullptr, DM, DM, DM, BIG, 2); // sigmoid(k)
    gemm(R16, Wv16, bv + i * DM, V16, nullptr, DM, DM, DM, BIG, 0);
    flow_attn<<<dim3(NB * NH), dim3(256), 0, stream>>>(Q16, K16, V16, V16); // O in-place
    gemm(V16, Wo16, bo + i * DM, nullptr, A32, DM, DM, DM, BIG, 0);
    ln_fused<<<ROWS / 4, 256, 0, stream>>>(R32, A32, ln1w + i * DM, ln1b + i * DM, R32, R16);
    gemm(R16, C116, c1b + i * DFF, F16, nullptr, DFF, DM, DFF, BIG, 1); // relu
    gemm(F16, C216, c2b + i * DM, nullptr, A32, DM, DFF, DM, BIG, 0);
    ln_fused<<<ROWS / 4, 256, 0, stream>>>(R32, A32, ln2w + i * DM, ln2b + i * DM, R32, R16);

    if (it < 4) {
      ca_zero<<<16, 256, 0, stream>>>(ybar);
      ca_mean<<<dim3(NB, 4, 8), 256, 0, stream>>>(R16, ybar);
      ca_gate<<<16, 256, 0, stream>>>(ybar, caw + i * 5, gate);
      ca_apply<<<(ROWS * DM / 4) / 256, 256, 0, stream>>>(R32, R16, gate);
    }
  }

  // ---- final LN + projection to C_OUT=64 (padded weight, guarded f32 stores)
  ln_fused<<<ROWS / 4, 256, 0, stream>>>(R32, nullptr, lnfw, lnfb, nullptr, U);
  pad_proj<<<(128 * DM + 255) / 256, 256, 0, stream>>>(projw, Wp);
  gemm(U, Wp, projb, nullptr, (float*)d_out, 128, DM, 64, 64, 0);

  (void)in_sizes; (void)n_in; (void)out_size; (void)ws_size;
}

// Round 3
// 2920.233 us; speedup vs baseline: 1.9941x; 1.9941x over previous
//
#include <hip/hip_runtime.h>
#include <stdint.h>

#define L_SEQ 2048
#define DM 1024
#define NH 16
#define DFF 4096
#define NB 4
#define ROWS (NB * L_SEQ)   // 8192

typedef __attribute__((ext_vector_type(8))) __bf16 bf16x8;
typedef __attribute__((ext_vector_type(4))) float f32x4;

__device__ __forceinline__ float bf2f(unsigned short u) {
  union { unsigned int i; float f; } x; x.i = ((unsigned int)u) << 16; return x.f;
}
__device__ __forceinline__ unsigned short f2bf(float f) {
  union { float f; unsigned int i; } x; x.f = f;
  unsigned int r = x.i + 0x7FFFu + ((x.i >> 16) & 1u);
  return (unsigned short)(r >> 16);
}

#if defined(__has_builtin)
#if __has_builtin(__builtin_amdgcn_global_load_lds)
#define HAVE_GLL 1
#endif
#endif
#ifndef HAVE_GLL
#define HAVE_GLL 0
#endif

typedef __attribute__((address_space(3))) void lds_void;
typedef const __attribute__((address_space(1))) void gbl_void;

__device__ __forceinline__ void stage16(const void* g, void* ldsbase, int lane) {
#if HAVE_GLL
  (void)lane;
  __builtin_amdgcn_global_load_lds((gbl_void*)g, (lds_void*)ldsbase, 16, 0, 0);
#else
  ((uint4*)ldsbase)[lane] = *(const uint4*)g;
#endif
}

// ---------------------------------------------------------------------------
// C[M=8192, N] = A[8192, K] * B[N, K]^T (+bias) (+act), bf16 in, f32 acc.
// ---------------------------------------------------------------------------
__global__ __launch_bounds__(256)
void gemm_bt(const unsigned short* __restrict__ A,
             const unsigned short* __restrict__ B,
             const float* __restrict__ bias,
             unsigned short* __restrict__ C16,
             float* __restrict__ C32,
             int K, int ldc, int n_limit, int act)
{
  __shared__ __attribute__((aligned(16))) unsigned short As[128 * 32];
  __shared__ __attribute__((aligned(16))) unsigned short Bs[128 * 32];
  const int tid  = threadIdx.x;
  const int wave = tid >> 6, lane = tid & 63;
  const int wm = (wave & 1) << 6, wn = (wave >> 1) << 6;
  const int l16 = lane & 15, quad = lane >> 4;

  const unsigned short* Ab = A + (size_t)blockIdx.x * 128 * K;
  const unsigned short* Bb = B + (size_t)blockIdx.y * 128 * K;

  const int srow = (wave << 4) + (lane >> 2);   // 0..63
  const int scol = (lane & 3) << 3;

  f32x4 acc[4][4] = {};

  for (int k0 = 0; k0 < K; k0 += 32) {
    const size_t aoff = (size_t)srow * K + k0 + scol;
    stage16(Ab + aoff,                  &As[(wave * 16) * 32],       lane);
    stage16(Ab + aoff + (size_t)64 * K, &As[(wave * 16 + 64) * 32], lane);
    stage16(Bb + aoff,                  &Bs[(wave * 16) * 32],       lane);
    stage16(Bb + aoff + (size_t)64 * K, &Bs[(wave * 16 + 64) * 32], lane);
    __syncthreads();

    bf16x8 af[4], bfr[4];
#pragma unroll
    for (int mi = 0; mi < 4; mi++)
      af[mi] = *(const bf16x8*)&As[(wm + mi * 16 + l16) * 32 + quad * 8];
#pragma unroll
    for (int ni = 0; ni < 4; ni++)
      bfr[ni] = *(const bf16x8*)&Bs[(wn + ni * 16 + l16) * 32 + quad * 8];
#pragma unroll
    for (int mi = 0; mi < 4; mi++)
#pragma unroll
      for (int ni = 0; ni < 4; ni++)
        acc[mi][ni] = __builtin_amdgcn_mfma_f32_16x16x32_bf16(af[mi], bfr[ni], acc[mi][ni], 0, 0, 0);
    __syncthreads();
  }

  const int row0 = (int)blockIdx.x * 128 + wm + quad * 4;
  const int col0 = (int)blockIdx.y * 128 + wn + l16;
#pragma unroll
  for (int ni = 0; ni < 4; ni++) {
    const int col = col0 + ni * 16;
    if (col >= n_limit) continue;
    const float bv = bias ? bias[col] : 0.0f;
#pragma unroll
    for (int mi = 0; mi < 4; mi++) {
#pragma unroll
      for (int r = 0; r < 4; r++) {
        const int row = row0 + mi * 16 + r;
        float v = acc[mi][ni][r] + bv;
        if (act == 1) v = fmaxf(v, 0.0f);
        else if (act == 2) v = 1.0f / (1.0f + __expf(-v));
        if (C32) C32[(size_t)row * ldc + col] = v;
        if (C16) C16[(size_t)row * ldc + col] = f2bf(v);
      }
    }
  }
}

// ===========================================================================
// Flow attention, grid-parallel decomposition.
// bh = b*16+h in [0,64); per-(b,h) slice base = b*L*DM + h*64.
// ===========================================================================

// ---- A1: ksum/qsum partials over 256-row chunks. grid(64,8), block 256.
__global__ __launch_bounds__(256)
void fa_sums(const unsigned short* __restrict__ Q, const unsigned short* __restrict__ K,
             float* __restrict__ ksp, float* __restrict__ qsp)
{
  const int bh = blockIdx.x, chunk = blockIdx.y;
  const size_t base = ((size_t)(bh >> 4) * L_SEQ) * DM + (size_t)(bh & 15) * 64;
  const int t = threadIdx.x, lane = t & 63, wave = t >> 6;
  __shared__ float red[256];
  float ks = 0.f, qs = 0.f;
  const int l0 = chunk * 256 + wave * 64;
  for (int i = 0; i < 64; i++) {
    const size_t idx = base + (size_t)(l0 + i) * DM + lane;
    ks += bf2f(K[idx]);
    qs += bf2f(Q[idx]);
  }
  red[t] = ks; __syncthreads();
  if (t < 64) ksp[(bh * 8 + chunk) * 64 + t] = red[t] + red[t + 64] + red[t + 128] + red[t + 192];
  __syncthreads();
  red[t] = qs; __syncthreads();
  if (t < 64) qsp[(bh * 8 + chunk) * 64 + t] = red[t] + red[t + 64] + red[t + 128] + red[t + 192];
}

// ---- A2+A3: per-row nr, nc; accumulate t1=sum k*nc, t2=sum q*nr partials.
// grid(64,16), block 256 (128 rows per block).
__global__ __launch_bounds__(256)
void fa_rows1(const unsigned short* __restrict__ Q, const unsigned short* __restrict__ K,
              const float* __restrict__ ksp, const float* __restrict__ qsp,
              float* __restrict__ nr, float* __restrict__ t1p, float* __restrict__ t2p)
{
  const int bh = blockIdx.x, chunk = blockIdx.y;
  const size_t base = ((size_t)(bh >> 4) * L_SEQ) * DM + (size_t)(bh & 15) * 64;
  const int t = threadIdx.x, lane = t & 63, wave = t >> 6;
  const float eps = 1e-6f;
  __shared__ float s_kse[64], s_qse[64], red[256];
  if (t < 64) {
    float s = 0.f;
    for (int j = 0; j < 8; j++) s += ksp[(bh * 8 + j) * 64 + t];
    s_kse[t] = s + eps;
  } else if (t < 128) {
    const int d = t - 64;
    float s = 0.f;
    for (int j = 0; j < 8; j++) s += qsp[(bh * 8 + j) * 64 + d];
    s_qse[d] = s + eps;
  }
  __syncthreads();
  const float kse = s_kse[lane], qse = s_qse[lane];
  float t1a = 0.f, t2a = 0.f;
  for (int i = 0; i < 32; i++) {
    const int l = chunk * 128 + wave + 4 * i;
    const size_t idx = base + (size_t)l * DM + lane;
    const float q = bf2f(Q[idx]), k = bf2f(K[idx]);
    float a = (q + eps) * kse;
    float c = (k + eps) * qse;
#pragma unroll
    for (int off = 32; off; off >>= 1) { a += __shfl_xor(a, off); c += __shfl_xor(c, off); }
    const float nrl = 1.f / a, ncl = 1.f / c;
    if (lane == 0) nr[bh * L_SEQ + l] = nrl;
    t1a += k * ncl;
    t2a += q * nrl;
  }
  red[t] = t1a; __syncthreads();
  if (t < 64) t1p[(bh * 16 + chunk) * 64 + t] = red[t] + red[t + 64] + red[t + 128] + red[t + 192];
  __syncthreads();
  red[t] = t2a; __syncthreads();
  if (t < 64) t2p[(bh * 16 + chunk) * 64 + t] = red[t] + red[t + 64] + red[t + 128] + red[t + 192];
}

// ---- A4: per-row nrr (folded into nr) and raw ncr score. grid(64,16).
__global__ __launch_bounds__(256)
void fa_rows2(const unsigned short* __restrict__ Q, const unsigned short* __restrict__ K,
              const float* __restrict__ t1p, const float* __restrict__ t2p,
              float* __restrict__ nr, float* __restrict__ sc)
{
  const int bh = blockIdx.x, chunk = blockIdx.y;
  const size_t base = ((size_t)(bh >> 4) * L_SEQ) * DM + (size_t)(bh & 15) * 64;
  const int t = threadIdx.x, lane = t & 63, wave = t >> 6;
  const float eps = 1e-6f;
  __shared__ float s_t1e[64], s_t2e[64];
  if (t < 64) {
    float s = 0.f;
    for (int j = 0; j < 16; j++) s += t1p[(bh * 16 + j) * 64 + t];
    s_t1e[t] = s + eps;
  } else if (t < 128) {
    const int d = t - 64;
    float s = 0.f;
    for (int j = 0; j < 16; j++) s += t2p[(bh * 16 + j) * 64 + d];
    s_t2e[d] = s + eps;
  }
  __syncthreads();
  const float t1e = s_t1e[lane], t2e = s_t2e[lane];
  for (int i = 0; i < 32; i++) {
    const int l = chunk * 128 + wave + 4 * i;
    const size_t idx = base + (size_t)l * DM + lane;
    const float q = bf2f(Q[idx]), k = bf2f(K[idx]);
    float a = (q + eps) * t1e;
    float c = (k + eps) * t2e;
#pragma unroll
    for (int off = 32; off; off >>= 1) { a += __shfl_xor(a, off); c += __shfl_xor(c, off); }
    if (lane == 0) {
      // Lq/S == 1 -> no extra scale on a
      nr[bh * L_SEQ + l] *= 1.f / (1.f + __expf(-a));
      sc[bh * L_SEQ + l] = c;
    }
  }
}

// ---- A5: softmax over L per bh, writes ncr into sc; zeroes kv[bh]. grid(64).
__global__ __launch_bounds__(256)
void fa_softmax(float* __restrict__ sc, float* __restrict__ kv)
{
  const int bh = blockIdx.x, t = threadIdx.x;
  __shared__ float red[256];
  float4* kvz = (float4*)(kv + bh * 64 * 64);
  for (int j = 0; j < 4; j++) kvz[t + 256 * j] = make_float4(0.f, 0.f, 0.f, 0.f);

  float* row = sc + bh * L_SEQ;
  float m = -3.4e38f;
  for (int l = t; l < L_SEQ; l += 256) m = fmaxf(m, row[l]);
  red[t] = m; __syncthreads();
  for (int s = 128; s > 0; s >>= 1) { if (t < s) red[t] = fmaxf(red[t], red[t + s]); __syncthreads(); }
  const float mx = red[0];
  __syncthreads();
  float ps = 0.f;
  float pv[8];
#pragma unroll
  for (int j = 0; j < 8; j++) {
    const int l = t + 256 * j;
    pv[j] = __expf(row[l] - mx);
    ps += pv[j];
  }
  red[t] = ps; __syncthreads();
  for (int s = 128; s > 0; s >>= 1) { if (t < s) red[t] += red[t + s]; __syncthreads(); }
  const float scale = (float)L_SEQ / red[0];
#pragma unroll
  for (int j = 0; j < 8; j++) row[t + 256 * j] = pv[j] * scale;
}

// ---- A6: kv[d][e] += sum_l k[l,d]*(v[l,e]*ncr[l]) over 128-row chunk (MFMA).
// grid(64,16), block 256. f32 atomicAdd into kv (16 colliding adds/addr).
__global__ __launch_bounds__(256)
void fa_kv(const unsigned short* __restrict__ K, const unsigned short* __restrict__ V,
           const float* __restrict__ sc, float* __restrict__ kv)
{
  const int bh = blockIdx.x, chunk = blockIdx.y;
  const size_t base = ((size_t)(bh >> 4) * L_SEQ) * DM + (size_t)(bh & 15) * 64;
  const int t = threadIdx.x, lane = t & 63, wave = t >> 6;
  const int l16 = lane & 15, quad = lane >> 4;
  __shared__ __attribute__((aligned(16))) unsigned short s_kT[64 * 72];
  __shared__ __attribute__((aligned(16))) unsigned short s_vT[64 * 72];

  f32x4 acc5[4] = {};
  for (int sub = 0; sub < 2; sub++) {
    const int l0 = chunk * 128 + sub * 64;
#pragma unroll
    for (int it = 0; it < 4; it++) {
      const int task = it * 256 + t;     // 0..1023
      const int l = task >> 4;           // 0..63
      const int g = task & 15;           // d-group of 4
      const size_t gidx = base + (size_t)(l0 + l) * DM + g * 4;
      const ushort4 k4 = *(const ushort4*)(K + gidx);
      const ushort4 v4 = *(const ushort4*)(V + gidx);
      const float wgt = sc[bh * L_SEQ + l0 + l];
      s_kT[(g * 4 + 0) * 72 + l] = k4.x;
      s_kT[(g * 4 + 1) * 72 + l] = k4.y;
      s_kT[(g * 4 + 2) * 72 + l] = k4.z;
      s_kT[(g * 4 + 3) * 72 + l] = k4.w;
      s_vT[(g * 4 + 0) * 72 + l] = f2bf(bf2f(v4.x) * wgt);
      s_vT[(g * 4 + 1) * 72 + l] = f2bf(bf2f(v4.y) * wgt);
      s_vT[(g * 4 + 2) * 72 + l] = f2bf(bf2f(v4.z) * wgt);
      s_vT[(g * 4 + 3) * 72 + l] = f2bf(bf2f(v4.w) * wgt);
    }
    __syncthreads();
#pragma unroll
    for (int ks = 0; ks < 2; ks++) {
      const bf16x8 af = *(const bf16x8*)&s_kT[(wave * 16 + l16) * 72 + ks * 32 + quad * 8];
#pragma unroll
      for (int et = 0; et < 4; et++) {
        const bf16x8 bf = *(const bf16x8*)&s_vT[(et * 16 + l16) * 72 + ks * 32 + quad * 8];
        acc5[et] = __builtin_amdgcn_mfma_f32_16x16x32_bf16(af, bf, acc5[et], 0, 0, 0);
      }
    }
    __syncthreads();
  }
  // C layout: d-row = wave*16 + quad*4 + r, e-col = et*16 + l16
#pragma unroll
  for (int et = 0; et < 4; et++)
#pragma unroll
    for (int r = 0; r < 4; r++)
      atomicAdd(&kv[bh * 4096 + (wave * 16 + quad * 4 + r) * 64 + et * 16 + l16], acc5[et][r]);
}

// ---- A7: O[l][e] = (sum_d q[l,d]*kv[d,e]) * nr'[l]. grid(64,16), block 256.
__global__ __launch_bounds__(256)
void fa_out(const unsigned short* __restrict__ Q, const float* __restrict__ kv,
            const float* __restrict__ nr, unsigned short* O)
{
  const int bh = blockIdx.x, chunk = blockIdx.y;
  const size_t base = ((size_t)(bh >> 4) * L_SEQ) * DM + (size_t)(bh & 15) * 64;
  const int t = threadIdx.x, lane = t & 63, wave = t >> 6;
  const int l16 = lane & 15, quad = lane >> 4;
  __shared__ __attribute__((aligned(16))) unsigned short s_kvT[64 * 72];  // [e][d]

#pragma unroll
  for (int j = 0; j < 16; j++) {
    const int i = t + 256 * j;       // i = d*64 + e
    const int d = i >> 6, e = i & 63;
    s_kvT[e * 72 + d] = f2bf(kv[bh * 4096 + i]);
  }
  __syncthreads();

  bf16x8 bfr6[4][2];
#pragma unroll
  for (int et = 0; et < 4; et++)
#pragma unroll
    for (int ks = 0; ks < 2; ks++)
      bfr6[et][ks] = *(const bf16x8*)&s_kvT[(et * 16 + l16) * 72 + ks * 32 + quad * 8];

#pragma unroll
  for (int ti = 0; ti < 2; ti++) {
    const int l0 = chunk * 128 + (wave * 2 + ti) * 16;
    f32x4 oc[4] = {};
#pragma unroll
    for (int ks = 0; ks < 2; ks++) {
      const bf16x8 aq = *(const bf16x8*)(Q + base + (size_t)(l0 + l16) * DM + ks * 32 + quad * 8);
#pragma unroll
      for (int et = 0; et < 4; et++)
        oc[et] = __builtin_amdgcn_mfma_f32_16x16x32_bf16(aq, bfr6[et][ks], oc[et], 0, 0, 0);
    }
#pragma unroll
    for (int r = 0; r < 4; r++) {
      const int l = l0 + quad * 4 + r;
      const float scl = nr[bh * L_SEQ + l];
#pragma unroll
      for (int et = 0; et < 4; et++)
        O[base + (size_t)l * DM + et * 16 + l16] = f2bf(oc[et][r] * scl);
    }
  }
}

// ---------------------------------------------------------------------------
// LayerNorm over last dim (1024): out = LN(res (+ add)) * w + b. 1 wave/row.
// ---------------------------------------------------------------------------
__global__ __launch_bounds__(256)
void ln_fused(const float* res, const float* __restrict__ add,
              const float* __restrict__ w, const float* __restrict__ bb,
              float* out32, unsigned short* out16)
{
  const int row = blockIdx.x * 4 + (threadIdx.x >> 6);
  const int lane = threadIdx.x & 63;
  const size_t roff = (size_t)row * DM;
  const float4* rp = (const float4*)(res + roff);
  const float4* ap = add ? (const float4*)(add + roff) : nullptr;

  float x[16], s = 0.f, s2 = 0.f;
#pragma unroll
  for (int q4 = 0; q4 < 4; q4++) {
    float4 v = rp[lane * 4 + q4];
    if (ap) { float4 a = ap[lane * 4 + q4]; v.x += a.x; v.y += a.y; v.z += a.z; v.w += a.w; }
    x[q4 * 4 + 0] = v.x; x[q4 * 4 + 1] = v.y; x[q4 * 4 + 2] = v.z; x[q4 * 4 + 3] = v.w;
    s += v.x + v.y + v.z + v.w;
    s2 += v.x * v.x + v.y * v.y + v.z * v.z + v.w * v.w;
  }
#pragma unroll
  for (int off = 32; off; off >>= 1) { s += __shfl_xor(s, off); s2 += __shfl_xor(s2, off); }
  const float mean = s * (1.f / DM);
  const float var = s2 * (1.f / DM) - mean * mean;
  const float rstd = rsqrtf(var + 1e-5f);
#pragma unroll
  for (int j = 0; j < 16; j++) {
    const int c = lane * 16 + j;
    x[j] = (x[j] - mean) * rstd * w[c] + bb[c];
  }
  if (out32) {
    float4* op = (float4*)(out32 + roff);
#pragma unroll
    for (int q4 = 0; q4 < 4; q4++) {
      float4 v; v.x = x[q4*4+0]; v.y = x[q4*4+1]; v.z = x[q4*4+2]; v.w = x[q4*4+3];
      op[lane * 4 + q4] = v;
    }
  }
  if (out16) {
#pragma unroll
    for (int q4 = 0; q4 < 4; q4++) {
      ushort4 u;
      u.x = f2bf(x[q4*4+0]); u.y = f2bf(x[q4*4+1]); u.z = f2bf(x[q4*4+2]); u.w = f2bf(x[q4*4+3]);
      *(ushort4*)(out16 + roff + lane * 16 + q4 * 4) = u;
    }
  }
}

// ---------------------------------------------------------------------------
// Channel attention helpers
// ---------------------------------------------------------------------------
__global__ void ca_zero(float* __restrict__ ybar) {
  const int i = blockIdx.x * 256 + threadIdx.x;
  if (i < NB * DM) ybar[i] = 0.f;
}
__global__ void ca_mean(const unsigned short* __restrict__ H16, float* __restrict__ ybar) {
  const int b = blockIdx.x, cc = blockIdx.y, lc = blockIdx.z;
  const int c = cc * 256 + threadIdx.x;
  float s = 0.f;
  for (int l = lc * 256; l < lc * 256 + 256; l++)
    s += bf2f(H16[((size_t)(b * L_SEQ + l)) * DM + c]);
  atomicAdd(&ybar[b * DM + c], s);
}
__global__ void ca_gate(const float* __restrict__ ybar, const float* __restrict__ cw,
                        float* __restrict__ gate) {
  const int i = blockIdx.x * 256 + threadIdx.x;
  if (i >= NB * DM) return;
  const int b = i >> 10, c = i & 1023;
  float acc = 0.f;
#pragma unroll
  for (int j = 0; j < 5; j++) {
    const int cc = c + j - 2;
    const float yv = (cc >= 0 && cc < DM) ? ybar[b * DM + cc] * (1.f / L_SEQ) : 0.f;
    acc += cw[j] * yv;
  }
  gate[i] = 1.f / (1.f + __expf(-acc));
}
__global__ void ca_apply(float* __restrict__ H32, unsigned short* __restrict__ H16,
                         const float* __restrict__ gate) {
  const size_t i = ((size_t)blockIdx.x * 256 + threadIdx.x) * 4;
  const int row = (int)(i >> 10);
  const int b = row >> 11;
  const int c = (int)(i & 1023);
  float4 v = *(float4*)(H32 + i);
  v.x *= gate[b * DM + c + 0];
  v.y *= gate[b * DM + c + 1];
  v.z *= gate[b * DM + c + 2];
  v.w *= gate[b * DM + c + 3];
  *(float4*)(H32 + i) = v;
  unsigned short* hp = H16 + i;
  hp[0] = f2bf(v.x); hp[1] = f2bf(v.y); hp[2] = f2bf(v.z); hp[3] = f2bf(v.w);
}

// ---------------------------------------------------------------------------
// f32 -> bf16 conversions
// ---------------------------------------------------------------------------
__global__ void embed_gather(const float* __restrict__ x, unsigned short* __restrict__ Ae) {
  const int i = blockIdx.x * 256 + threadIdx.x;
  if (i >= ROWS * 192) return;
  const int row = i / 192, kk = i % 192;
  const int t3 = kk >> 6, c = kk & 63;
  const int b = row >> 11, l = row & 2047;
  const int ls = (l + t3 - 1 + L_SEQ) & 2047;
  Ae[i] = f2bf(x[((size_t)(b * L_SEQ + ls)) * 64 + c]);
}
__global__ void embed_repack(const float* __restrict__ w, unsigned short* __restrict__ We) {
  const int i = blockIdx.x * 256 + threadIdx.x;
  if (i >= DM * 192) return;
  const int f = i / 192, kk = i % 192;
  const int t3 = kk >> 6, c = kk & 63;
  We[i] = f2bf(w[(f * 64 + c) * 3 + t3]);
}
__global__ void pad_proj(const float* __restrict__ pw, unsigned short* __restrict__ Wp) {
  const int i = blockIdx.x * 256 + threadIdx.x;
  if (i >= 128 * DM) return;
  Wp[i] = ((i >> 10) < 64) ? f2bf(pw[i]) : (unsigned short)0;
}
// 12M scalar elements as 3M float4s: [0,4M): Wq/Wk/Wv/Wo (1M each); [4M,12M): c1,c2 (4M each)
__global__ void cvt_layer_weights(const float* __restrict__ Wq, const float* __restrict__ Wk,
                                  const float* __restrict__ Wv, const float* __restrict__ Wo,
                                  const float* __restrict__ c1, const float* __restrict__ c2,
                                  unsigned short* __restrict__ Wl, unsigned short* __restrict__ WlFF) {
  const int g = blockIdx.x * 256 + threadIdx.x;   // 0..3M-1 float4 units
  const int i = g << 2;                           // scalar index
  const float* src; unsigned short* dst;
  if (i < (1 << 22)) {
    const int w = i >> 20, off = i & ((1 << 20) - 1);
    const float* srcs[4] = {Wq, Wk, Wv, Wo};
    src = srcs[w] + off; dst = Wl + (w << 20) + off;
  } else {
    const int j = i - (1 << 22);
    const int w = j >> 22, off = j & ((1 << 22) - 1);
    src = (w ? c2 : c1) + off; dst = WlFF + (w << 22) + off;
  }
  const float4 v = *(const float4*)src;
  ushort4 u; u.x = f2bf(v.x); u.y = f2bf(v.y); u.z = f2bf(v.z); u.w = f2bf(v.w);
  *(ushort4*)dst = u;
}

// ---------------------------------------------------------------------------
extern "C" void kernel_launch(void* const* d_in, const int* in_sizes, int n_in,
                              void* d_out, int out_size, void* d_ws, size_t ws_size,
                              hipStream_t stream) {
  const float* x     = (const float*)d_in[0];
  const float* tokw  = (const float*)d_in[1];
  const float* Wq    = (const float*)d_in[2];
  const float* bq    = (const float*)d_in[3];
  const float* Wk    = (const float*)d_in[4];
  const float* bk    = (const float*)d_in[5];
  const float* Wv    = (const float*)d_in[6];
  const float* bv    = (const float*)d_in[7];
  const float* Wo    = (const float*)d_in[8];
  const float* bo    = (const float*)d_in[9];
  const float* c1w   = (const float*)d_in[10];
  const float* c1b   = (const float*)d_in[11];
  const float* c2w   = (const float*)d_in[12];
  const float* c2b   = (const float*)d_in[13];
  const float* ln1w  = (const float*)d_in[14];
  const float* ln1b  = (const float*)d_in[15];
  const float* ln2w  = (const float*)d_in[16];
  const float* ln2b  = (const float*)d_in[17];
  const float* caw   = (const float*)d_in[18];
  const float* lnfw  = (const float*)d_in[19];
  const float* lnfb  = (const float*)d_in[20];
  const float* projw = (const float*)d_in[21];
  const float* projb = (const float*)d_in[22];

  char* ws = (char*)d_ws;
  float*          R32 = (float*)(ws);                               // 32 MB
  unsigned short* R16 = (unsigned short*)(ws + ((size_t)32 << 20)); // 16 MB
  float*          A32 = (float*)(ws + ((size_t)48 << 20));          // 32 MB
  unsigned short* U   = (unsigned short*)(ws + ((size_t)80 << 20)); // 64 MB
  unsigned short* Q16 = U;                                          // 16 MB
  unsigned short* K16 = U + ((size_t)8 << 20);                      // 16 MB
  unsigned short* V16 = U + ((size_t)16 << 20);                     // 16 MB
  unsigned short* F16 = U;                                          // 64 MB (FFN)
  // Flow-attention scratch lives in U's tail (128..144 MB abs offset):
  // free during attention (QKV use first 48 MB), clobbered later by FFN F16.
  char* fa = ws + ((size_t)128 << 20);
  float* fa_nr  = (float*)(fa);                    // 512 KB [64][2048]
  float* fa_sc  = (float*)(fa + (512 << 10));      // 512 KB [64][2048]
  float* fa_ksp = (float*)(fa + (1024 << 10));     // 128 KB [64][8][64]
  float* fa_qsp = (float*)(fa + (1152 << 10));     // 128 KB
  float* fa_t1p = (float*)(fa + (1280 << 10));     // 512 KB [64][16][64]
  float* fa_t2p = (float*)(fa + (1792 << 10));     // 512 KB
  float* fa_kvb = (float*)(fa + (2304 << 10));     // 1 MB  [64][64][64]
  unsigned short* Wl   = (unsigned short*)(ws + ((size_t)144 << 20)); // 8 MB
  unsigned short* WlFF = (unsigned short*)(ws + ((size_t)152 << 20)); // 16 MB
  char* misc = ws + ((size_t)168 << 20);
  float*          ybar = (float*)misc;                              // 16 KB
  float*          gate = (float*)(misc + (16 << 10));               // 16 KB
  unsigned short* We   = (unsigned short*)(misc + (64 << 10));      // 384 KB
  unsigned short* Wp   = (unsigned short*)(misc + (512 << 10));     // 256 KB

  const int BIG = 1 << 30;
  auto gemm = [&](const unsigned short* A, const unsigned short* B, const float* bias,
                  unsigned short* C16, float* C32, int N, int K, int ldc, int nlim, int act) {
    dim3 grid(ROWS / 128, N / 128);
    gemm_bt<<<grid, dim3(256), 0, stream>>>(A, B, bias, C16, C32, K, ldc, nlim, act);
  };

  // ---- token embedding (circular conv k=3 as im2col GEMM) -> R (f32 + bf16)
  embed_gather<<<(ROWS * 192 + 255) / 256, 256, 0, stream>>>(x, U);
  embed_repack<<<(DM * 192 + 255) / 256, 256, 0, stream>>>(tokw, We);
  gemm(U, We, nullptr, R16, R32, DM, 192, DM, BIG, 0);

  // ---- 4 encoder layers (+CA), then layer 3 re-applied (faithful to reference)
  for (int it = 0; it < 5; it++) {
    const int i = (it < 4) ? it : 3;
    if (it != 4) {  // it==4 reuses layer-3 weights already converted at it==3
      cvt_layer_weights<<<(3 << 20) / 256, 256, 0, stream>>>(
          Wq + ((size_t)i << 20), Wk + ((size_t)i << 20),
          Wv + ((size_t)i << 20), Wo + ((size_t)i << 20),
          c1w + ((size_t)i << 22), c2w + ((size_t)i << 22), Wl, WlFF);
    }
    const unsigned short* Wq16 = Wl;
    const unsigned short* Wk16 = Wl + (1 << 20);
    const unsigned short* Wv16 = Wl + (2 << 20);
    const unsigned short* Wo16 = Wl + (3 << 20);
    const unsigned short* C116 = WlFF;
    const unsigned short* C216 = WlFF + (1 << 22);

    gemm(R16, Wq16, bq + i * DM, Q16, nullptr, DM, DM, DM, BIG, 2); // sigmoid(q)
    gemm(R16, Wk16, bk + i * DM, K16, nullptr, DM, DM, DM, BIG, 2); // sigmoid(k)
    gemm(R16, Wv16, bv + i * DM, V16, nullptr, DM, DM, DM, BIG, 0);

    // flow attention (grid-parallel)
    fa_sums   <<<dim3(64, 8),  256, 0, stream>>>(Q16, K16, fa_ksp, fa_qsp);
    fa_rows1  <<<dim3(64, 16), 256, 0, stream>>>(Q16, K16, fa_ksp, fa_qsp, fa_nr, fa_t1p, fa_t2p);
    fa_rows2  <<<dim3(64, 16), 256, 0, stream>>>(Q16, K16, fa_t1p, fa_t2p, fa_nr, fa_sc);
    fa_softmax<<<dim3(64),     256, 0, stream>>>(fa_sc, fa_kvb);
    fa_kv     <<<dim3(64, 16), 256, 0, stream>>>(K16, V16, fa_sc, fa_kvb);
    fa_out    <<<dim3(64, 16), 256, 0, stream>>>(Q16, fa_kvb, fa_nr, V16); // O over V

    gemm(V16, Wo16, bo + i * DM, nullptr, A32, DM, DM, DM, BIG, 0);
    ln_fused<<<ROWS / 4, 256, 0, stream>>>(R32, A32, ln1w + i * DM, ln1b + i * DM, R32, R16);
    gemm(R16, C116, c1b + i * DFF, F16, nullptr, DFF, DM, DFF, BIG, 1); // relu
    gemm(F16, C216, c2b + i * DM, nullptr, A32, DM, DFF, DM, BIG, 0);
    ln_fused<<<ROWS / 4, 256, 0, stream>>>(R32, A32, ln2w + i * DM, ln2b + i * DM, R32, R16);

    if (it < 4) {
      ca_zero<<<16, 256, 0, stream>>>(ybar);
      ca_mean<<<dim3(NB, 4, 8), 256, 0, stream>>>(R16, ybar);
      ca_gate<<<16, 256, 0, stream>>>(ybar, caw + i * 5, gate);
      ca_apply<<<(ROWS * DM / 4) / 256, 256, 0, stream>>>(R32, R16, gate);
    }
  }

  // ---- final LN + projection to C_OUT=64 (padded weight, guarded f32 stores)
  ln_fused<<<ROWS / 4, 256, 0, stream>>>(R32, nullptr, lnfw, lnfb, nullptr, U);
  pad_proj<<<(128 * DM + 255) / 256, 256, 0, stream>>>(projw, Wp);
  gemm(U, Wp, projb, nullptr, (float*)d_out, 128, DM, 64, 64, 0);

  (void)in_sizes; (void)n_in; (void)out_size; (void)ws_size;
}

// Round 4
// 2822.309 us; speedup vs baseline: 2.0632x; 1.0347x over previous
//
#include <hip/hip_runtime.h>
#include <stdint.h>

#define L_SEQ 2048
#define DM 1024
#define NH 16
#define DFF 4096
#define NB 4
#define ROWS (NB * L_SEQ)   // 8192

typedef __attribute__((ext_vector_type(8))) __bf16 bf16x8;
typedef __attribute__((ext_vector_type(4))) float f32x4;

__device__ __forceinline__ float bf2f(unsigned short u) {
  union { unsigned int i; float f; } x; x.i = ((unsigned int)u) << 16; return x.f;
}
__device__ __forceinline__ unsigned short f2bf(float f) {
  union { float f; unsigned int i; } x; x.f = f;
  unsigned int r = x.i + 0x7FFFu + ((x.i >> 16) & 1u);
  return (unsigned short)(r >> 16);
}

typedef __attribute__((address_space(3))) void lds_void;
typedef const __attribute__((address_space(1))) void gbl_void;

// Forced global_load_lds (gfx950): lane i's 16 bytes land at base + i*16.
__device__ __forceinline__ void stage16(const void* g, void* ldsbase) {
  __builtin_amdgcn_global_load_lds((gbl_void*)g, (lds_void*)ldsbase, 16, 0, 0);
}

// ---------------------------------------------------------------------------
// C[M=8192, N] = A[8192, K] * B[N, K]^T (+bias) (+act), bf16 in, f32 acc.
// A row stride = lda (>= K). act: 0=none, 1=relu, 2=sigmoid, 3=sigmoid iff col<2048.
// ---------------------------------------------------------------------------
__global__ __launch_bounds__(256)
void gemm_bt(const unsigned short* __restrict__ A,
             const unsigned short* __restrict__ B,
             const float* __restrict__ bias,
             unsigned short* __restrict__ C16,
             float* __restrict__ C32,
             int K, int lda, int ldc, int n_limit, int act)
{
  __shared__ __attribute__((aligned(16))) unsigned short As[128 * 32];
  __shared__ __attribute__((aligned(16))) unsigned short Bs[128 * 32];
  const int tid  = threadIdx.x;
  const int wave = tid >> 6, lane = tid & 63;
  const int wm = (wave & 1) << 6, wn = (wave >> 1) << 6;
  const int l16 = lane & 15, quad = lane >> 4;

  const unsigned short* Ab = A + (size_t)blockIdx.x * 128 * lda;
  const unsigned short* Bb = B + (size_t)blockIdx.y * 128 * K;

  const int srow = (wave << 4) + (lane >> 2);   // 0..63
  const int scol = (lane & 3) << 3;

  f32x4 acc[4][4] = {};

  for (int k0 = 0; k0 < K; k0 += 32) {
    const size_t aoff = (size_t)srow * lda + k0 + scol;
    const size_t boff = (size_t)srow * K   + k0 + scol;
    stage16(Ab + aoff,                    &As[(wave * 16) * 32]);
    stage16(Ab + aoff + (size_t)64 * lda, &As[(wave * 16 + 64) * 32]);
    stage16(Bb + boff,                    &Bs[(wave * 16) * 32]);
    stage16(Bb + boff + (size_t)64 * K,   &Bs[(wave * 16 + 64) * 32]);
    __syncthreads();

    bf16x8 af[4], bfr[4];
#pragma unroll
    for (int mi = 0; mi < 4; mi++)
      af[mi] = *(const bf16x8*)&As[(wm + mi * 16 + l16) * 32 + quad * 8];
#pragma unroll
    for (int ni = 0; ni < 4; ni++)
      bfr[ni] = *(const bf16x8*)&Bs[(wn + ni * 16 + l16) * 32 + quad * 8];
#pragma unroll
    for (int mi = 0; mi < 4; mi++)
#pragma unroll
      for (int ni = 0; ni < 4; ni++)
        acc[mi][ni] = __builtin_amdgcn_mfma_f32_16x16x32_bf16(af[mi], bfr[ni], acc[mi][ni], 0, 0, 0);
    __syncthreads();
  }

  const int row0 = (int)blockIdx.x * 128 + wm + quad * 4;
  const int col0 = (int)blockIdx.y * 128 + wn + l16;
#pragma unroll
  for (int ni = 0; ni < 4; ni++) {
    const int col = col0 + ni * 16;
    if (col >= n_limit) continue;
    const float bv = bias ? bias[col] : 0.0f;
    const bool sig = (act == 2) || (act == 3 && col < 2048);
#pragma unroll
    for (int mi = 0; mi < 4; mi++) {
#pragma unroll
      for (int r = 0; r < 4; r++) {
        const int row = row0 + mi * 16 + r;
        float v = acc[mi][ni][r] + bv;
        if (act == 1) v = fmaxf(v, 0.0f);
        else if (sig) v = 1.0f / (1.0f + __expf(-v));
        if (C32) C32[(size_t)row * ldc + col] = v;
        if (C16) C16[(size_t)row * ldc + col] = f2bf(v);
      }
    }
  }
}

// ===========================================================================
// Flow attention, grid-parallel decomposition. Q,K,V share row stride ld.
// bh = b*16+h in [0,64); per-(b,h) slice base = b*L*ld + h*64.
// ===========================================================================

// ---- A1: ksum/qsum partials over 256-row chunks. grid(64,8), block 256.
__global__ __launch_bounds__(256)
void fa_sums(const unsigned short* __restrict__ Q, const unsigned short* __restrict__ K,
             int ld, float* __restrict__ ksp, float* __restrict__ qsp)
{
  const int bh = blockIdx.x, chunk = blockIdx.y;
  const size_t base = ((size_t)(bh >> 4) * L_SEQ) * ld + (size_t)(bh & 15) * 64;
  const int t = threadIdx.x, lane = t & 63, wave = t >> 6;
  __shared__ float red[256];
  float ks = 0.f, qs = 0.f;
  const int l0 = chunk * 256 + wave * 64;
  for (int i = 0; i < 64; i++) {
    const size_t idx = base + (size_t)(l0 + i) * ld + lane;
    ks += bf2f(K[idx]);
    qs += bf2f(Q[idx]);
  }
  red[t] = ks; __syncthreads();
  if (t < 64) ksp[(bh * 8 + chunk) * 64 + t] = red[t] + red[t + 64] + red[t + 128] + red[t + 192];
  __syncthreads();
  red[t] = qs; __syncthreads();
  if (t < 64) qsp[(bh * 8 + chunk) * 64 + t] = red[t] + red[t + 64] + red[t + 128] + red[t + 192];
}

// ---- A2+A3: per-row nr, nc; accumulate t1=sum k*nc, t2=sum q*nr partials.
__global__ __launch_bounds__(256)
void fa_rows1(const unsigned short* __restrict__ Q, const unsigned short* __restrict__ K,
              int ld, const float* __restrict__ ksp, const float* __restrict__ qsp,
              float* __restrict__ nr, float* __restrict__ t1p, float* __restrict__ t2p)
{
  const int bh = blockIdx.x, chunk = blockIdx.y;
  const size_t base = ((size_t)(bh >> 4) * L_SEQ) * ld + (size_t)(bh & 15) * 64;
  const int t = threadIdx.x, lane = t & 63, wave = t >> 6;
  const float eps = 1e-6f;
  __shared__ float s_kse[64], s_qse[64], red[256];
  if (t < 64) {
    float s = 0.f;
    for (int j = 0; j < 8; j++) s += ksp[(bh * 8 + j) * 64 + t];
    s_kse[t] = s + eps;
  } else if (t < 128) {
    const int d = t - 64;
    float s = 0.f;
    for (int j = 0; j < 8; j++) s += qsp[(bh * 8 + j) * 64 + d];
    s_qse[d] = s + eps;
  }
  __syncthreads();
  const float kse = s_kse[lane], qse = s_qse[lane];
  float t1a = 0.f, t2a = 0.f;
  for (int i = 0; i < 32; i++) {
    const int l = chunk * 128 + wave + 4 * i;
    const size_t idx = base + (size_t)l * ld + lane;
    const float q = bf2f(Q[idx]), k = bf2f(K[idx]);
    float a = (q + eps) * kse;
    float c = (k + eps) * qse;
#pragma unroll
    for (int off = 32; off; off >>= 1) { a += __shfl_xor(a, off); c += __shfl_xor(c, off); }
    const float nrl = 1.f / a, ncl = 1.f / c;
    if (lane == 0) nr[bh * L_SEQ + l] = nrl;
    t1a += k * ncl;
    t2a += q * nrl;
  }
  red[t] = t1a; __syncthreads();
  if (t < 64) t1p[(bh * 16 + chunk) * 64 + t] = red[t] + red[t + 64] + red[t + 128] + red[t + 192];
  __syncthreads();
  red[t] = t2a; __syncthreads();
  if (t < 64) t2p[(bh * 16 + chunk) * 64 + t] = red[t] + red[t + 64] + red[t + 128] + red[t + 192];
}

// ---- A4: per-row nrr (folded into nr) and raw ncr score. grid(64,16).
__global__ __launch_bounds__(256)
void fa_rows2(const unsigned short* __restrict__ Q, const unsigned short* __restrict__ K,
              int ld, const float* __restrict__ t1p, const float* __restrict__ t2p,
              float* __restrict__ nr, float* __restrict__ sc)
{
  const int bh = blockIdx.x, chunk = blockIdx.y;
  const size_t base = ((size_t)(bh >> 4) * L_SEQ) * ld + (size_t)(bh & 15) * 64;
  const int t = threadIdx.x, lane = t & 63, wave = t >> 6;
  const float eps = 1e-6f;
  __shared__ float s_t1e[64], s_t2e[64];
  if (t < 64) {
    float s = 0.f;
    for (int j = 0; j < 16; j++) s += t1p[(bh * 16 + j) * 64 + t];
    s_t1e[t] = s + eps;
  } else if (t < 128) {
    const int d = t - 64;
    float s = 0.f;
    for (int j = 0; j < 16; j++) s += t2p[(bh * 16 + j) * 64 + d];
    s_t2e[d] = s + eps;
  }
  __syncthreads();
  const float t1e = s_t1e[lane], t2e = s_t2e[lane];
  for (int i = 0; i < 32; i++) {
    const int l = chunk * 128 + wave + 4 * i;
    const size_t idx = base + (size_t)l * ld + lane;
    const float q = bf2f(Q[idx]), k = bf2f(K[idx]);
    float a = (q + eps) * t1e;
    float c = (k + eps) * t2e;
#pragma unroll
    for (int off = 32; off; off >>= 1) { a += __shfl_xor(a, off); c += __shfl_xor(c, off); }
    if (lane == 0) {
      nr[bh * L_SEQ + l] *= 1.f / (1.f + __expf(-a));
      sc[bh * L_SEQ + l] = c;
    }
  }
}

// ---- A5: softmax over L per bh, writes ncr into sc; zeroes kv[bh]. grid(64).
__global__ __launch_bounds__(256)
void fa_softmax(float* __restrict__ sc, float* __restrict__ kv)
{
  const int bh = blockIdx.x, t = threadIdx.x;
  __shared__ float red[256];
  float4* kvz = (float4*)(kv + bh * 64 * 64);
  for (int j = 0; j < 4; j++) kvz[t + 256 * j] = make_float4(0.f, 0.f, 0.f, 0.f);

  float* row = sc + bh * L_SEQ;
  float m = -3.4e38f;
  for (int l = t; l < L_SEQ; l += 256) m = fmaxf(m, row[l]);
  red[t] = m; __syncthreads();
  for (int s = 128; s > 0; s >>= 1) { if (t < s) red[t] = fmaxf(red[t], red[t + s]); __syncthreads(); }
  const float mx = red[0];
  __syncthreads();
  float ps = 0.f;
  float pv[8];
#pragma unroll
  for (int j = 0; j < 8; j++) {
    const int l = t + 256 * j;
    pv[j] = __expf(row[l] - mx);
    ps += pv[j];
  }
  red[t] = ps; __syncthreads();
  for (int s = 128; s > 0; s >>= 1) { if (t < s) red[t] += red[t + s]; __syncthreads(); }
  const float scale = (float)L_SEQ / red[0];
#pragma unroll
  for (int j = 0; j < 8; j++) row[t + 256 * j] = pv[j] * scale;
}

// ---- A6: kv[d][e] += sum_l k[l,d]*(v[l,e]*ncr[l]) over 128-row chunk (MFMA).
__global__ __launch_bounds__(256)
void fa_kv(const unsigned short* __restrict__ K, const unsigned short* __restrict__ V,
           int ld, const float* __restrict__ sc, float* __restrict__ kv)
{
  const int bh = blockIdx.x, chunk = blockIdx.y;
  const size_t base = ((size_t)(bh >> 4) * L_SEQ) * ld + (size_t)(bh & 15) * 64;
  const int t = threadIdx.x, lane = t & 63, wave = t >> 6;
  const int l16 = lane & 15, quad = lane >> 4;
  __shared__ __attribute__((aligned(16))) unsigned short s_kT[64 * 72];
  __shared__ __attribute__((aligned(16))) unsigned short s_vT[64 * 72];

  f32x4 acc5[4] = {};
  for (int sub = 0; sub < 2; sub++) {
    const int l0 = chunk * 128 + sub * 64;
#pragma unroll
    for (int it = 0; it < 4; it++) {
      const int task = it * 256 + t;     // 0..1023
      const int l = task >> 4;           // 0..63
      const int g = task & 15;           // d-group of 4
      const size_t gidx = base + (size_t)(l0 + l) * ld + g * 4;
      const ushort4 k4 = *(const ushort4*)(K + gidx);
      const ushort4 v4 = *(const ushort4*)(V + gidx);
      const float wgt = sc[bh * L_SEQ + l0 + l];
      s_kT[(g * 4 + 0) * 72 + l] = k4.x;
      s_kT[(g * 4 + 1) * 72 + l] = k4.y;
      s_kT[(g * 4 + 2) * 72 + l] = k4.z;
      s_kT[(g * 4 + 3) * 72 + l] = k4.w;
      s_vT[(g * 4 + 0) * 72 + l] = f2bf(bf2f(v4.x) * wgt);
      s_vT[(g * 4 + 1) * 72 + l] = f2bf(bf2f(v4.y) * wgt);
      s_vT[(g * 4 + 2) * 72 + l] = f2bf(bf2f(v4.z) * wgt);
      s_vT[(g * 4 + 3) * 72 + l] = f2bf(bf2f(v4.w) * wgt);
    }
    __syncthreads();
#pragma unroll
    for (int ks = 0; ks < 2; ks++) {
      const bf16x8 af = *(const bf16x8*)&s_kT[(wave * 16 + l16) * 72 + ks * 32 + quad * 8];
#pragma unroll
      for (int et = 0; et < 4; et++) {
        const bf16x8 bf = *(const bf16x8*)&s_vT[(et * 16 + l16) * 72 + ks * 32 + quad * 8];
        acc5[et] = __builtin_amdgcn_mfma_f32_16x16x32_bf16(af, bf, acc5[et], 0, 0, 0);
      }
    }
    __syncthreads();
  }
#pragma unroll
  for (int et = 0; et < 4; et++)
#pragma unroll
    for (int r = 0; r < 4; r++)
      atomicAdd(&kv[bh * 4096 + (wave * 16 + quad * 4 + r) * 64 + et * 16 + l16], acc5[et][r]);
}

// ---- A7: O[l][e] = (sum_d q[l,d]*kv[d,e]) * nr'[l]. grid(64,16), block 256.
__global__ __launch_bounds__(256)
void fa_out(const unsigned short* __restrict__ Q, int ld, const float* __restrict__ kv,
            const float* __restrict__ nr, unsigned short* O)
{
  const int bh = blockIdx.x, chunk = blockIdx.y;
  const size_t base = ((size_t)(bh >> 4) * L_SEQ) * ld + (size_t)(bh & 15) * 64;
  const int t = threadIdx.x, lane = t & 63, wave = t >> 6;
  const int l16 = lane & 15, quad = lane >> 4;
  __shared__ __attribute__((aligned(16))) unsigned short s_kvT[64 * 72];  // [e][d]

#pragma unroll
  for (int j = 0; j < 16; j++) {
    const int i = t + 256 * j;       // i = d*64 + e
    const int d = i >> 6, e = i & 63;
    s_kvT[e * 72 + d] = f2bf(kv[bh * 4096 + i]);
  }
  __syncthreads();

  bf16x8 bfr6[4][2];
#pragma unroll
  for (int et = 0; et < 4; et++)
#pragma unroll
    for (int ks = 0; ks < 2; ks++)
      bfr6[et][ks] = *(const bf16x8*)&s_kvT[(et * 16 + l16) * 72 + ks * 32 + quad * 8];

#pragma unroll
  for (int ti = 0; ti < 2; ti++) {
    const int l0 = chunk * 128 + (wave * 2 + ti) * 16;
    f32x4 oc[4] = {};
#pragma unroll
    for (int ks = 0; ks < 2; ks++) {
      const bf16x8 aq = *(const bf16x8*)(Q + base + (size_t)(l0 + l16) * ld + ks * 32 + quad * 8);
#pragma unroll
      for (int et = 0; et < 4; et++)
        oc[et] = __builtin_amdgcn_mfma_f32_16x16x32_bf16(aq, bfr6[et][ks], oc[et], 0, 0, 0);
    }
#pragma unroll
    for (int r = 0; r < 4; r++) {
      const int l = l0 + quad * 4 + r;
      const float scl = nr[bh * L_SEQ + l];
#pragma unroll
      for (int et = 0; et < 4; et++)
        O[base + (size_t)l * ld + et * 16 + l16] = f2bf(oc[et][r] * scl);
    }
  }
}

// ---------------------------------------------------------------------------
// LayerNorm over last dim (1024): out = LN(res (+ add)) * w + b. 1 wave/row.
// ---------------------------------------------------------------------------
__global__ __launch_bounds__(256)
void ln_fused(const float* res, const float* __restrict__ add,
              const float* __restrict__ w, const float* __restrict__ bb,
              float* out32, unsigned short* out16)
{
  const int row = blockIdx.x * 4 + (threadIdx.x >> 6);
  const int lane = threadIdx.x & 63;
  const size_t roff = (size_t)row * DM;
  const float4* rp = (const float4*)(res + roff);
  const float4* ap = add ? (const float4*)(add + roff) : nullptr;

  float x[16], s = 0.f, s2 = 0.f;
#pragma unroll
  for (int q4 = 0; q4 < 4; q4++) {
    float4 v = rp[lane * 4 + q4];
    if (ap) { float4 a = ap[lane * 4 + q4]; v.x += a.x; v.y += a.y; v.z += a.z; v.w += a.w; }
    x[q4 * 4 + 0] = v.x; x[q4 * 4 + 1] = v.y; x[q4 * 4 + 2] = v.z; x[q4 * 4 + 3] = v.w;
    s += v.x + v.y + v.z + v.w;
    s2 += v.x * v.x + v.y * v.y + v.z * v.z + v.w * v.w;
  }
#pragma unroll
  for (int off = 32; off; off >>= 1) { s += __shfl_xor(s, off); s2 += __shfl_xor(s2, off); }
  const float mean = s * (1.f / DM);
  const float var = s2 * (1.f / DM) - mean * mean;
  const float rstd = rsqrtf(var + 1e-5f);
#pragma unroll
  for (int j = 0; j < 16; j++) {
    const int c = lane * 16 + j;
    x[j] = (x[j] - mean) * rstd * w[c] + bb[c];
  }
  if (out32) {
    float4* op = (float4*)(out32 + roff);
#pragma unroll
    for (int q4 = 0; q4 < 4; q4++) {
      float4 v; v.x = x[q4*4+0]; v.y = x[q4*4+1]; v.z = x[q4*4+2]; v.w = x[q4*4+3];
      op[lane * 4 + q4] = v;
    }
  }
  if (out16) {
#pragma unroll
    for (int q4 = 0; q4 < 4; q4++) {
      ushort4 u;
      u.x = f2bf(x[q4*4+0]); u.y = f2bf(x[q4*4+1]); u.z = f2bf(x[q4*4+2]); u.w = f2bf(x[q4*4+3]);
      *(ushort4*)(out16 + roff + lane * 16 + q4 * 4) = u;
    }
  }
}

// ---------------------------------------------------------------------------
// Channel attention helpers
// ---------------------------------------------------------------------------
__global__ void ca_zero(float* __restrict__ ybar) {
  const int i = blockIdx.x * 256 + threadIdx.x;
  if (i < NB * DM) ybar[i] = 0.f;
}
__global__ void ca_mean(const unsigned short* __restrict__ H16, float* __restrict__ ybar) {
  const int b = blockIdx.x, cc = blockIdx.y, lc = blockIdx.z;
  const int c = cc * 256 + threadIdx.x;
  float s = 0.f;
  for (int l = lc * 256; l < lc * 256 + 256; l++)
    s += bf2f(H16[((size_t)(b * L_SEQ + l)) * DM + c]);
  atomicAdd(&ybar[b * DM + c], s);
}
__global__ void ca_gate(const float* __restrict__ ybar, const float* __restrict__ cw,
                        float* __restrict__ gate) {
  const int i = blockIdx.x * 256 + threadIdx.x;
  if (i >= NB * DM) return;
  const int b = i >> 10, c = i & 1023;
  float acc = 0.f;
#pragma unroll
  for (int j = 0; j < 5; j++) {
    const int cc = c + j - 2;
    const float yv = (cc >= 0 && cc < DM) ? ybar[b * DM + cc] * (1.f / L_SEQ) : 0.f;
    acc += cw[j] * yv;
  }
  gate[i] = 1.f / (1.f + __expf(-acc));
}
__global__ void ca_apply(float* __restrict__ H32, unsigned short* __restrict__ H16,
                         const float* __restrict__ gate) {
  const size_t i = ((size_t)blockIdx.x * 256 + threadIdx.x) * 4;
  const int row = (int)(i >> 10);
  const int b = row >> 11;
  const int c = (int)(i & 1023);
  float4 v = *(float4*)(H32 + i);
  v.x *= gate[b * DM + c + 0];
  v.y *= gate[b * DM + c + 1];
  v.z *= gate[b * DM + c + 2];
  v.w *= gate[b * DM + c + 3];
  *(float4*)(H32 + i) = v;
  unsigned short* hp = H16 + i;
  hp[0] = f2bf(v.x); hp[1] = f2bf(v.y); hp[2] = f2bf(v.z); hp[3] = f2bf(v.w);
}

// ---------------------------------------------------------------------------
// f32 -> bf16 conversions
// ---------------------------------------------------------------------------
__global__ void embed_gather(const float* __restrict__ x, unsigned short* __restrict__ Ae) {
  const int i = blockIdx.x * 256 + threadIdx.x;
  if (i >= ROWS * 192) return;
  const int row = i / 192, kk = i % 192;
  const int t3 = kk >> 6, c = kk & 63;
  const int b = row >> 11, l = row & 2047;
  const int ls = (l + t3 - 1 + L_SEQ) & 2047;
  Ae[i] = f2bf(x[((size_t)(b * L_SEQ + ls)) * 64 + c]);
}
__global__ void embed_repack(const float* __restrict__ w, unsigned short* __restrict__ We) {
  const int i = blockIdx.x * 256 + threadIdx.x;
  if (i >= DM * 192) return;
  const int f = i / 192, kk = i % 192;
  const int t3 = kk >> 6, c = kk & 63;
  We[i] = f2bf(w[(f * 64 + c) * 3 + t3]);
}
__global__ void pad_proj(const float* __restrict__ pw, unsigned short* __restrict__ Wp) {
  const int i = blockIdx.x * 256 + threadIdx.x;
  if (i >= 128 * DM) return;
  Wp[i] = ((i >> 10) < 64) ? f2bf(pw[i]) : (unsigned short)0;
}
__global__ void pack_qkv_bias(const float* __restrict__ bq, const float* __restrict__ bk,
                              const float* __restrict__ bv, float* __restrict__ bqkv) {
  const int i = blockIdx.x * 256 + threadIdx.x;   // 0..3071
  if (i >= 3072) return;
  bqkv[i] = (i < 1024) ? bq[i] : (i < 2048 ? bk[i - 1024] : bv[i - 2048]);
}
// 12M scalar elements as 3M float4s: [0,4M): Wq/Wk/Wv/Wo (1M each); [4M,12M): c1,c2 (4M each)
__global__ void cvt_layer_weights(const float* __restrict__ Wq, const float* __restrict__ Wk,
                                  const float* __restrict__ Wv, const float* __restrict__ Wo,
                                  const float* __restrict__ c1, const float* __restrict__ c2,
                                  unsigned short* __restrict__ Wl, unsigned short* __restrict__ WlFF) {
  const int g = blockIdx.x * 256 + threadIdx.x;   // 0..3M-1 float4 units
  const int i = g << 2;                           // scalar index
  const float* src; unsigned short* dst;
  if (i < (1 << 22)) {
    const int w = i >> 20, off = i & ((1 << 20) - 1);
    const float* srcs[4] = {Wq, Wk, Wv, Wo};
    src = srcs[w] + off; dst = Wl + (w << 20) + off;
  } else {
    const int j = i - (1 << 22);
    const int w = j >> 22, off = j & ((1 << 22) - 1);
    src = (w ? c2 : c1) + off; dst = WlFF + (w << 22) + off;
  }
  const float4 v = *(const float4*)src;
  ushort4 u; u.x = f2bf(v.x); u.y = f2bf(v.y); u.z = f2bf(v.z); u.w = f2bf(v.w);
  *(ushort4*)dst = u;
}

// ---------------------------------------------------------------------------
extern "C" void kernel_launch(void* const* d_in, const int* in_sizes, int n_in,
                              void* d_out, int out_size, void* d_ws, size_t ws_size,
                              hipStream_t stream) {
  const float* x     = (const float*)d_in[0];
  const float* tokw  = (const float*)d_in[1];
  const float* Wq    = (const float*)d_in[2];
  const float* bq    = (const float*)d_in[3];
  const float* Wk    = (const float*)d_in[4];
  const float* bk    = (const float*)d_in[5];
  const float* Wv    = (const float*)d_in[6];
  const float* bv    = (const float*)d_in[7];
  const float* Wo    = (const float*)d_in[8];
  const float* bo    = (const float*)d_in[9];
  const float* c1w   = (const float*)d_in[10];
  const float* c1b   = (const float*)d_in[11];
  const float* c2w   = (const float*)d_in[12];
  const float* c2b   = (const float*)d_in[13];
  const float* ln1w  = (const float*)d_in[14];
  const float* ln1b  = (const float*)d_in[15];
  const float* ln2w  = (const float*)d_in[16];
  const float* ln2b  = (const float*)d_in[17];
  const float* caw   = (const float*)d_in[18];
  const float* lnfw  = (const float*)d_in[19];
  const float* lnfb  = (const float*)d_in[20];
  const float* projw = (const float*)d_in[21];
  const float* projb = (const float*)d_in[22];

  char* ws = (char*)d_ws;
  float*          R32 = (float*)(ws);                               // 32 MB
  unsigned short* R16 = (unsigned short*)(ws + ((size_t)32 << 20)); // 16 MB
  float*          A32 = (float*)(ws + ((size_t)48 << 20));          // 32 MB
  unsigned short* U   = (unsigned short*)(ws + ((size_t)80 << 20)); // 64 MB
  unsigned short* QKV16 = U;                       // 48 MB: [8192][3072] (Q|K|V cols)
  unsigned short* F16   = U;                       // 64 MB (FFN phase)
  char* fa = ws + ((size_t)128 << 20);
  float* fa_nr  = (float*)(fa);                    // 512 KB [64][2048]
  float* fa_sc  = (float*)(fa + (512 << 10));      // 512 KB [64][2048]
  float* fa_ksp = (float*)(fa + (1024 << 10));     // 128 KB [64][8][64]
  float* fa_qsp = (float*)(fa + (1152 << 10));     // 128 KB
  float* fa_t1p = (float*)(fa + (1280 << 10));     // 512 KB [64][16][64]
  float* fa_t2p = (float*)(fa + (1792 << 10));     // 512 KB
  float* fa_kvb = (float*)(fa + (2304 << 10));     // 1 MB  [64][64][64]
  unsigned short* Wl   = (unsigned short*)(ws + ((size_t)144 << 20)); // 8 MB  [Wq|Wk|Wv|Wo]
  unsigned short* WlFF = (unsigned short*)(ws + ((size_t)152 << 20)); // 16 MB [c1|c2]
  char* misc = ws + ((size_t)168 << 20);
  float*          ybar = (float*)misc;                              // 16 KB
  float*          gate = (float*)(misc + (16 << 10));               // 16 KB
  float*          bqkv = (float*)(misc + (32 << 10));               // 12 KB
  unsigned short* We   = (unsigned short*)(misc + (64 << 10));      // 384 KB
  unsigned short* Wp   = (unsigned short*)(misc + (512 << 10));     // 256 KB

  const int BIG = 1 << 30;
  auto gemm = [&](const unsigned short* A, const unsigned short* B, const float* bias,
                  unsigned short* C16, float* C32, int N, int K, int lda, int ldc,
                  int nlim, int act) {
    dim3 grid(ROWS / 128, N / 128);
    gemm_bt<<<grid, dim3(256), 0, stream>>>(A, B, bias, C16, C32, K, lda, ldc, nlim, act);
  };

  // ---- token embedding (circular conv k=3 as im2col GEMM) -> R (f32 + bf16)
  embed_gather<<<(ROWS * 192 + 255) / 256, 256, 0, stream>>>(x, U);
  embed_repack<<<(DM * 192 + 255) / 256, 256, 0, stream>>>(tokw, We);
  gemm(U, We, nullptr, R16, R32, DM, 192, 192, DM, BIG, 0);

  // ---- 4 encoder layers (+CA), then layer 3 re-applied (faithful to reference)
  for (int it = 0; it < 5; it++) {
    const int i = (it < 4) ? it : 3;
    if (it != 4) {  // it==4 reuses layer-3 weights/bias already converted at it==3
      cvt_layer_weights<<<(3 << 20) / 256, 256, 0, stream>>>(
          Wq + ((size_t)i << 20), Wk + ((size_t)i << 20),
          Wv + ((size_t)i << 20), Wo + ((size_t)i << 20),
          c1w + ((size_t)i << 22), c2w + ((size_t)i << 22), Wl, WlFF);
      pack_qkv_bias<<<12, 256, 0, stream>>>(bq + i * DM, bk + i * DM, bv + i * DM, bqkv);
    }
    const unsigned short* Wo16 = Wl + (3 << 20);
    const unsigned short* C116 = WlFF;
    const unsigned short* C216 = WlFF + (1 << 22);

    // fused QKV GEMM: N=3072, sigmoid on Q,K columns (<2048) only
    gemm(R16, Wl, bqkv, QKV16, nullptr, 3072, DM, DM, 3072, BIG, 3);

    const unsigned short* Qp = QKV16;
    const unsigned short* Kp = QKV16 + 1024;
    unsigned short*       Vp = QKV16 + 2048;   // O written in place over V

    fa_sums   <<<dim3(64, 8),  256, 0, stream>>>(Qp, Kp, 3072, fa_ksp, fa_qsp);
    fa_rows1  <<<dim3(64, 16), 256, 0, stream>>>(Qp, Kp, 3072, fa_ksp, fa_qsp, fa_nr, fa_t1p, fa_t2p);
    fa_rows2  <<<dim3(64, 16), 256, 0, stream>>>(Qp, Kp, 3072, fa_t1p, fa_t2p, fa_nr, fa_sc);
    fa_softmax<<<dim3(64),     256, 0, stream>>>(fa_sc, fa_kvb);
    fa_kv     <<<dim3(64, 16), 256, 0, stream>>>(Kp, Vp, 3072, fa_sc, fa_kvb);
    fa_out    <<<dim3(64, 16), 256, 0, stream>>>(Qp, 3072, fa_kvb, fa_nr, Vp);

    gemm(Vp, Wo16, bo + i * DM, nullptr, A32, DM, DM, 3072, DM, BIG, 0);
    ln_fused<<<ROWS / 4, 256, 0, stream>>>(R32, A32, ln1w + i * DM, ln1b + i * DM, R32, R16);
    gemm(R16, C116, c1b + i * DFF, F16, nullptr, DFF, DM, DM, DFF, BIG, 1); // relu
    gemm(F16, C216, c2b + i * DM, nullptr, A32, DM, DFF, DFF, DM, BIG, 0);
    ln_fused<<<ROWS / 4, 256, 0, stream>>>(R32, A32, ln2w + i * DM, ln2b + i * DM, R32, R16);

    if (it < 4) {
      ca_zero<<<16, 256, 0, stream>>>(ybar);
      ca_mean<<<dim3(NB, 4, 8), 256, 0, stream>>>(R16, ybar);
      ca_gate<<<16, 256, 0, stream>>>(ybar, caw + i * 5, gate);
      ca_apply<<<(ROWS * DM / 4) / 256, 256, 0, stream>>>(R32, R16, gate);
    }
  }

  // ---- final LN + projection to C_OUT=64 (padded weight, guarded f32 stores)
  ln_fused<<<ROWS / 4, 256, 0, stream>>>(R32, nullptr, lnfw, lnfb, nullptr, U);
  pad_proj<<<(128 * DM + 255) / 256, 256, 0, stream>>>(projw, Wp);
  gemm(U, Wp, projb, nullptr, (float*)d_out, 128, DM, DM, 64, 64, 0);

  (void)in_sizes; (void)n_in; (void)out_size; (void)ws_size;
}